// Round 1
// baseline (800.387 us; speedup 1.0000x reference)
//
#include <hip/hip_runtime.h>
#include <hip/hip_bf16.h>
#include <cstdint>

#define NN 8192      // N = B*K nodes
#define EE 1024      // E = B*P edges
#define DD 256       // ZDIM
#define KK_SEL 819   // int(0.1 * 8192)

// ---------------------------------------------------------------------------
// Kernel 1: simi[e][n] = dot(hyper_clss[e], x[n]),  e in [0,1024), n in [0,8192)
// hyper_clss[e] = hyper_params[y[e>>4]*16 + (e&15)]
// Tiled fp32 GEMM: 64x64 tile, BK=32, 256 threads, 4x4 micro-tile.
// ---------------------------------------------------------------------------
__global__ __launch_bounds__(256) void simi_gemm(
    const float* __restrict__ x, const int* __restrict__ y,
    const float* __restrict__ hyper, float* __restrict__ simi) {
  __shared__ float As[32][68];  // [k][e], pad to 68 (16B-aligned rows, spread banks)
  __shared__ float Bs[32][68];  // [k][n]
  const int tid = threadIdx.x;
  const int bi = blockIdx.y;  // e-tile (16)
  const int bj = blockIdx.x;  // n-tile (128)
  const int ty = tid >> 4, tx = tid & 15;
  const int i0 = ty * 4, j0 = tx * 4;
  float acc[4][4] = {};

  for (int k0 = 0; k0 < DD; k0 += 32) {
    // load 64 rows x 32 k for A and B, 2 phases of 256 threads x float4
#pragma unroll
    for (int p = 0; p < 2; ++p) {
      int f = p * 256 + tid;        // [0,512)
      int le = f >> 3;              // row within tile [0,64)
      int kq = (f & 7) * 4;         // k offset [0,32)
      int eg = bi * 64 + le;
      int cls = y[eg >> 4];
      const float* srcA = hyper + ((size_t)(cls * 16 + (eg & 15))) * DD + k0 + kq;
      float4 va = *(const float4*)srcA;
      As[kq + 0][le] = va.x; As[kq + 1][le] = va.y;
      As[kq + 2][le] = va.z; As[kq + 3][le] = va.w;
      int ng = bj * 64 + le;
      const float4 vb = *(const float4*)(x + (size_t)ng * DD + k0 + kq);
      Bs[kq + 0][le] = vb.x; Bs[kq + 1][le] = vb.y;
      Bs[kq + 2][le] = vb.z; Bs[kq + 3][le] = vb.w;
    }
    __syncthreads();
#pragma unroll
    for (int kk = 0; kk < 32; ++kk) {
      float4 a4 = *(const float4*)&As[kk][i0];
      float4 b4 = *(const float4*)&Bs[kk][j0];
      float av[4] = {a4.x, a4.y, a4.z, a4.w};
      float bv[4] = {b4.x, b4.y, b4.z, b4.w};
#pragma unroll
      for (int i = 0; i < 4; ++i)
#pragma unroll
        for (int j = 0; j < 4; ++j) acc[i][j] += av[i] * bv[j];
    }
    __syncthreads();
  }
#pragma unroll
  for (int i = 0; i < 4; ++i) {
    int e = bi * 64 + i0 + i;
    float4 o = {acc[i][0], acc[i][1], acc[i][2], acc[i][3]};
    *(float4*)&simi[(size_t)e * NN + bj * 64 + j0] = o;
  }
}

// ---------------------------------------------------------------------------
// Kernel 2: per edge e, radix-select the 819th largest of simi[e][:] (exact),
// write thr[e]; then DE[e] = count(simi[e][:] > thr[e]).
// Order-preserving key: k = sign ? ~u : (u | 0x80000000)  (ascending).
// Want ascending rank r = 8192 - 819 = 7373 (0-based).
// ---------------------------------------------------------------------------
__global__ __launch_bounds__(256) void select_thr(
    const float* __restrict__ simi, float* __restrict__ thr, int* __restrict__ DE) {
  const int e = blockIdx.x;
  const float* row = simi + (size_t)e * NN;
  __shared__ unsigned hist[256];
  __shared__ unsigned sh_prefix;
  __shared__ int sh_r;
  __shared__ int red[256];
  const int tid = threadIdx.x;
  if (tid == 0) { sh_prefix = 0u; sh_r = NN - KK_SEL; }
  __syncthreads();

  for (int pass = 0; pass < 4; ++pass) {
    const int shift = 24 - pass * 8;
    for (int b = tid; b < 256; b += 256) hist[b] = 0u;
    __syncthreads();
    const unsigned prefix = sh_prefix;
    const unsigned pmask = (pass == 0) ? 0u : (0xFFFFFFFFu << (shift + 8));
    for (int i = tid; i < NN; i += 256) {
      unsigned u = __float_as_uint(row[i]);
      unsigned k = (u & 0x80000000u) ? ~u : (u | 0x80000000u);
      if ((k & pmask) == prefix) atomicAdd(&hist[(k >> shift) & 0xFFu], 1u);
    }
    __syncthreads();
    if (tid == 0) {
      unsigned cum = 0;
      int r = sh_r;
      for (int b = 0; b < 256; ++b) {
        unsigned h = hist[b];
        if (cum + h > (unsigned)r) {
          sh_prefix = sh_prefix | ((unsigned)b << shift);
          sh_r = r - (int)cum;
          break;
        }
        cum += h;
      }
    }
    __syncthreads();
  }
  const unsigned key = sh_prefix;
  const unsigned u = (key & 0x80000000u) ? (key & 0x7FFFFFFFu) : ~key;
  const float t = __uint_as_float(u);

  int cnt = 0;
  for (int i = tid; i < NN; i += 256) cnt += (row[i] > t) ? 1 : 0;
  red[tid] = cnt;
  __syncthreads();
  for (int s = 128; s > 0; s >>= 1) {
    if (tid < s) red[tid] += red[tid + s];
    __syncthreads();
  }
  if (tid == 0) { thr[e] = t; DE[e] = red[0]; }
}

// ---------------------------------------------------------------------------
// Kernel 3: build H bitmasks (16 u64 per node), DV2[n] = DV^-0.5
// ---------------------------------------------------------------------------
__global__ __launch_bounds__(256) void build_h(
    const float* __restrict__ simi, const float* __restrict__ thr,
    unsigned long long* __restrict__ Hbits, float* __restrict__ DV2) {
  __shared__ float sthr[EE];
  const int tid = threadIdx.x;
  for (int e = tid; e < EE; e += 256) sthr[e] = thr[e];
  __syncthreads();
  const int n = blockIdx.x * 256 + tid;
  int dv = 0;
#pragma unroll 1
  for (int w = 0; w < 16; ++w) {
    unsigned long long m = 0ull;
#pragma unroll 8
    for (int b = 0; b < 64; ++b) {
      const int e = w * 64 + b;
      const float v = simi[(size_t)e * NN + n];
      m |= ((unsigned long long)(v > sthr[e])) << b;
    }
    Hbits[(size_t)n * 16 + w] = m;
    dv += __popcll(m);
  }
  DV2[n] = 1.0f / sqrtf((float)dv);
}

// ---------------------------------------------------------------------------
// Kernel 4: find mode of DE, build exception list (edges with DE != mode).
// modeInfo: [0]=mode, [1]=NX, [2]=bits(invMode)
// ---------------------------------------------------------------------------
__global__ __launch_bounds__(256) void mode_exc(
    const int* __restrict__ DE, int* __restrict__ modeInfo,
    int* __restrict__ exc_idx, float* __restrict__ exc_delta) {
  __shared__ unsigned hist[1024];
  __shared__ int s_mode;
  __shared__ int s_cnt;
  const int tid = threadIdx.x;
  for (int i = tid; i < 1024; i += 256) hist[i] = 0u;
  __syncthreads();
  for (int e = tid; e < EE; e += 256) atomicAdd(&hist[DE[e]], 1u);
  __syncthreads();
  if (tid == 0) {
    int best = 1; unsigned bc = 0;
    for (int i = 0; i < 1024; ++i)
      if (hist[i] > bc) { bc = hist[i]; best = i; }
    s_mode = best; s_cnt = 0;
  }
  __syncthreads();
  const int mode = s_mode;
  const float invMode = 1.0f / (float)mode;
  for (int e = tid; e < EE; e += 256) {
    const int de = DE[e];
    if (de != mode) {
      const int idx = atomicAdd(&s_cnt, 1);
      exc_idx[idx] = e;
      exc_delta[idx] = 1.0f / (float)de - invMode;
    }
  }
  __syncthreads();
  if (tid == 0) {
    modeInfo[0] = s_mode;
    modeInfo[1] = s_cnt;
    modeInfo[2] = __float_as_int(invMode);
  }
}

// ---------------------------------------------------------------------------
// Kernel 5: G[n,m] = DV2[n]*DV2[m]*(popcount(Hn&Hm)*invMode + corrections)
// 64x64 tile per 256-thread block, 4x4 per thread.
// ---------------------------------------------------------------------------
__global__ __launch_bounds__(256) void g_kernel(
    const unsigned long long* __restrict__ Hbits, const float* __restrict__ DV2,
    const int* __restrict__ modeInfo, const int* __restrict__ exc_idx,
    const float* __restrict__ exc_delta, float* __restrict__ G) {
  __shared__ unsigned long long rowM[64][17];
  __shared__ unsigned long long colM[64][17];
  __shared__ float rDV2[64], cDV2[64];
  const int bi = blockIdx.y, bj = blockIdx.x;
  const int tid = threadIdx.x;
  for (int i = tid; i < 1024; i += 256) {
    const int rr = i >> 4, ww = i & 15;
    rowM[rr][ww] = Hbits[(size_t)(bi * 64 + rr) * 16 + ww];
    colM[rr][ww] = Hbits[(size_t)(bj * 64 + rr) * 16 + ww];
  }
  if (tid < 64) {
    rDV2[tid] = DV2[bi * 64 + tid];
    cDV2[tid] = DV2[bj * 64 + tid];
  }
  __syncthreads();

  const int ty = tid >> 4, tx = tid & 15;
  const int i0 = ty * 4, j0 = tx * 4;
  unsigned cnt[4][4] = {};
#pragma unroll
  for (int w = 0; w < 16; ++w) {
    unsigned long long a0 = rowM[i0 + 0][w], a1 = rowM[i0 + 1][w];
    unsigned long long a2 = rowM[i0 + 2][w], a3 = rowM[i0 + 3][w];
    unsigned long long b0 = colM[j0 + 0][w], b1 = colM[j0 + 1][w];
    unsigned long long b2 = colM[j0 + 2][w], b3 = colM[j0 + 3][w];
    cnt[0][0] += __popcll(a0 & b0); cnt[0][1] += __popcll(a0 & b1);
    cnt[0][2] += __popcll(a0 & b2); cnt[0][3] += __popcll(a0 & b3);
    cnt[1][0] += __popcll(a1 & b0); cnt[1][1] += __popcll(a1 & b1);
    cnt[1][2] += __popcll(a1 & b2); cnt[1][3] += __popcll(a1 & b3);
    cnt[2][0] += __popcll(a2 & b0); cnt[2][1] += __popcll(a2 & b1);
    cnt[2][2] += __popcll(a2 & b2); cnt[2][3] += __popcll(a2 & b3);
    cnt[3][0] += __popcll(a3 & b0); cnt[3][1] += __popcll(a3 & b1);
    cnt[3][2] += __popcll(a3 & b2); cnt[3][3] += __popcll(a3 & b3);
  }

  const float invMode = __int_as_float(modeInfo[2]);
  const int NX = modeInfo[1];
  float corr[4][4] = {};
  for (int xx = 0; xx < NX; ++xx) {
    const int e = exc_idx[xx];
    const float dlt = exc_delta[xx];
    const int w = e >> 6, b = e & 63;
#pragma unroll
    for (int i = 0; i < 4; ++i) {
      const unsigned long long rb = (rowM[i0 + i][w] >> b) & 1ull;
#pragma unroll
      for (int j = 0; j < 4; ++j) {
        const unsigned long long cb = (colM[j0 + j][w] >> b) & 1ull;
        corr[i][j] += dlt * (float)(rb & cb);
      }
    }
  }

#pragma unroll
  for (int i = 0; i < 4; ++i) {
    const int row = bi * 64 + i0 + i;
    const float dr = rDV2[i0 + i];
    float4 o;
    o.x = dr * cDV2[j0 + 0] * ((float)cnt[i][0] * invMode + corr[i][0]);
    o.y = dr * cDV2[j0 + 1] * ((float)cnt[i][1] * invMode + corr[i][1]);
    o.z = dr * cDV2[j0 + 2] * ((float)cnt[i][2] * invMode + corr[i][2]);
    o.w = dr * cDV2[j0 + 3] * ((float)cnt[i][3] * invMode + corr[i][3]);
    *(float4*)&G[(size_t)row * NN + bj * 64 + j0] = o;
  }
}

// ---------------------------------------------------------------------------
extern "C" void kernel_launch(void* const* d_in, const int* in_sizes, int n_in,
                              void* d_out, int out_size, void* d_ws, size_t ws_size,
                              hipStream_t stream) {
  const float* x = (const float*)d_in[0];        // [64,128,256]
  const int* y = (const int*)d_in[1];            // [64]
  const float* hyper = (const float*)d_in[2];    // [100,16,256]
  float* out = (float*)d_out;                    // G [8192*8192] then hyper_x [8192*256]

  // simi (32 MB) lives inside d_out's G region (G written only afterwards)
  float* simi = out;

  uint8_t* w8 = (uint8_t*)d_ws;
  float* thr = (float*)(w8 + 0);                            // 4 KB
  int* DE = (int*)(w8 + 4096);                              // 4 KB
  float* DV2 = (float*)(w8 + 8192);                         // 32 KB
  int* modeInfo = (int*)(w8 + 40960);                       // 16 B
  int* exc_idx = (int*)(w8 + 41984);                        // 4 KB
  float* exc_delta = (float*)(w8 + 46080);                  // 4 KB
  unsigned long long* Hbits = (unsigned long long*)(w8 + 65536);  // 1 MB

  // 1. simi = hc @ x^T
  simi_gemm<<<dim3(NN / 64, EE / 64), 256, 0, stream>>>(x, y, hyper, simi);
  // 2. per-edge threshold (exact 819th largest) + DE
  select_thr<<<dim3(EE), 256, 0, stream>>>(simi, thr, DE);
  // 3. H bitmasks + DV^-1/2
  build_h<<<dim3(NN / 256), 256, 0, stream>>>(simi, thr, Hbits, DV2);
  // 4. DE mode + exceptions
  mode_exc<<<dim3(1), 256, 0, stream>>>(DE, modeInfo, exc_idx, exc_delta);
  // 5. G via bitwise popcount
  g_kernel<<<dim3(NN / 64, NN / 64), 256, 0, stream>>>(Hbits, DV2, modeInfo,
                                                       exc_idx, exc_delta, out);
  // 6. hyper_x = x (8 MB d2d)
  hipMemcpyAsync(out + (size_t)NN * NN, x, (size_t)NN * DD * sizeof(float),
                 hipMemcpyDeviceToDevice, stream);
}

// Round 2
// 559.987 us; speedup vs baseline: 1.4293x; 1.4293x over previous
//
#include <hip/hip_runtime.h>
#include <hip/hip_bf16.h>
#include <cstdint>

#define NN 8192      // N = B*K nodes
#define EE 1024      // E = B*P edges
#define DD 256       // ZDIM
#define KK_SEL 819   // int(0.1 * 8192)

typedef __attribute__((ext_vector_type(4))) int int32x4;

// ---------------------------------------------------------------------------
// Kernel 1: simi[e][n] = dot(hyper_clss[e], x[n])  (fp32, exact)
// ---------------------------------------------------------------------------
__global__ __launch_bounds__(256) void simi_gemm(
    const float* __restrict__ x, const int* __restrict__ y,
    const float* __restrict__ hyper, float* __restrict__ simi) {
  __shared__ float As[32][68];
  __shared__ float Bs[32][68];
  const int tid = threadIdx.x;
  const int bi = blockIdx.y;  // e-tile (16)
  const int bj = blockIdx.x;  // n-tile (128)
  const int ty = tid >> 4, tx = tid & 15;
  const int i0 = ty * 4, j0 = tx * 4;
  float acc[4][4] = {};

  for (int k0 = 0; k0 < DD; k0 += 32) {
#pragma unroll
    for (int p = 0; p < 2; ++p) {
      int f = p * 256 + tid;
      int le = f >> 3;
      int kq = (f & 7) * 4;
      int eg = bi * 64 + le;
      int cls = y[eg >> 4];
      const float* srcA = hyper + ((size_t)(cls * 16 + (eg & 15))) * DD + k0 + kq;
      float4 va = *(const float4*)srcA;
      As[kq + 0][le] = va.x; As[kq + 1][le] = va.y;
      As[kq + 2][le] = va.z; As[kq + 3][le] = va.w;
      int ng = bj * 64 + le;
      const float4 vb = *(const float4*)(x + (size_t)ng * DD + k0 + kq);
      Bs[kq + 0][le] = vb.x; Bs[kq + 1][le] = vb.y;
      Bs[kq + 2][le] = vb.z; Bs[kq + 3][le] = vb.w;
    }
    __syncthreads();
#pragma unroll
    for (int kk = 0; kk < 32; ++kk) {
      float4 a4 = *(const float4*)&As[kk][i0];
      float4 b4 = *(const float4*)&Bs[kk][j0];
      float av[4] = {a4.x, a4.y, a4.z, a4.w};
      float bv[4] = {b4.x, b4.y, b4.z, b4.w};
#pragma unroll
      for (int i = 0; i < 4; ++i)
#pragma unroll
        for (int j = 0; j < 4; ++j) acc[i][j] += av[i] * bv[j];
    }
    __syncthreads();
  }
#pragma unroll
  for (int i = 0; i < 4; ++i) {
    int e = bi * 64 + i0 + i;
    float4 o = {acc[i][0], acc[i][1], acc[i][2], acc[i][3]};
    *(float4*)&simi[(size_t)e * NN + bj * 64 + j0] = o;
  }
}

// ---------------------------------------------------------------------------
// Kernel 2: exact radix-select of the 819th largest per edge + DE count
// ---------------------------------------------------------------------------
__global__ __launch_bounds__(256) void select_thr(
    const float* __restrict__ simi, float* __restrict__ thr, int* __restrict__ DE) {
  const int e = blockIdx.x;
  const float* row = simi + (size_t)e * NN;
  __shared__ unsigned hist[256];
  __shared__ unsigned sh_prefix;
  __shared__ int sh_r;
  __shared__ int red[256];
  const int tid = threadIdx.x;
  if (tid == 0) { sh_prefix = 0u; sh_r = NN - KK_SEL; }
  __syncthreads();

  for (int pass = 0; pass < 4; ++pass) {
    const int shift = 24 - pass * 8;
    for (int b = tid; b < 256; b += 256) hist[b] = 0u;
    __syncthreads();
    const unsigned prefix = sh_prefix;
    const unsigned pmask = (pass == 0) ? 0u : (0xFFFFFFFFu << (shift + 8));
    for (int i = tid; i < NN; i += 256) {
      unsigned u = __float_as_uint(row[i]);
      unsigned k = (u & 0x80000000u) ? ~u : (u | 0x80000000u);
      if ((k & pmask) == prefix) atomicAdd(&hist[(k >> shift) & 0xFFu], 1u);
    }
    __syncthreads();
    if (tid == 0) {
      unsigned cum = 0;
      int r = sh_r;
      for (int b = 0; b < 256; ++b) {
        unsigned h = hist[b];
        if (cum + h > (unsigned)r) {
          sh_prefix = sh_prefix | ((unsigned)b << shift);
          sh_r = r - (int)cum;
          break;
        }
        cum += h;
      }
    }
    __syncthreads();
  }
  const unsigned key = sh_prefix;
  const unsigned u = (key & 0x80000000u) ? (key & 0x7FFFFFFFu) : ~key;
  const float t = __uint_as_float(u);

  int cnt = 0;
  for (int i = tid; i < NN; i += 256) cnt += (row[i] > t) ? 1 : 0;
  red[tid] = cnt;
  __syncthreads();
  for (int s = 128; s > 0; s >>= 1) {
    if (tid < s) red[tid] += red[tid + s];
    __syncthreads();
  }
  if (tid == 0) { thr[e] = t; DE[e] = red[0]; }
}

// ---------------------------------------------------------------------------
// Kernel 3: H bitmasks (16 u64 per node) + DV2[n] = DV^-0.5
// ---------------------------------------------------------------------------
__global__ __launch_bounds__(256) void build_h(
    const float* __restrict__ simi, const float* __restrict__ thr,
    unsigned long long* __restrict__ Hbits, float* __restrict__ DV2) {
  __shared__ float sthr[EE];
  const int tid = threadIdx.x;
  for (int e = tid; e < EE; e += 256) sthr[e] = thr[e];
  __syncthreads();
  const int n = blockIdx.x * 256 + tid;
  int dv = 0;
#pragma unroll 1
  for (int w = 0; w < 16; ++w) {
    unsigned long long m = 0ull;
#pragma unroll 8
    for (int b = 0; b < 64; ++b) {
      const int e = w * 64 + b;
      const float v = simi[(size_t)e * NN + n];
      m |= ((unsigned long long)(v > sthr[e])) << b;
    }
    Hbits[(size_t)n * 16 + w] = m;
    dv += __popcll(m);
  }
  DV2[n] = 1.0f / sqrtf((float)dv);
}

// ---------------------------------------------------------------------------
// Kernel 3b: expand Hbits -> H8 (i8 0/1, node-major [8192][1024]), coalesced
// ---------------------------------------------------------------------------
__global__ __launch_bounds__(256) void h8_expand(
    const unsigned long long* __restrict__ Hbits, unsigned char* __restrict__ H8) {
  const int idx = blockIdx.x * 256 + threadIdx.x;  // [0, 8192*64)
  const int n = idx >> 6;
  const int c16 = idx & 63;
  const unsigned long long w = Hbits[(size_t)n * 16 + (c16 >> 2)];
  const unsigned int b16 = (unsigned int)((w >> ((c16 & 3) * 16)) & 0xFFFFull);
  uint4 u;
  u.x = ((b16 >> 0) & 1u) | (((b16 >> 1) & 1u) << 8) | (((b16 >> 2) & 1u) << 16) | (((b16 >> 3) & 1u) << 24);
  u.y = ((b16 >> 4) & 1u) | (((b16 >> 5) & 1u) << 8) | (((b16 >> 6) & 1u) << 16) | (((b16 >> 7) & 1u) << 24);
  u.z = ((b16 >> 8) & 1u) | (((b16 >> 9) & 1u) << 8) | (((b16 >> 10) & 1u) << 16) | (((b16 >> 11) & 1u) << 24);
  u.w = ((b16 >> 12) & 1u) | (((b16 >> 13) & 1u) << 8) | (((b16 >> 14) & 1u) << 16) | (((b16 >> 15) & 1u) << 24);
  *(uint4*)(H8 + (size_t)n * EE + c16 * 16) = u;
}

// ---------------------------------------------------------------------------
// Kernel 4: DE mode + exception list
// ---------------------------------------------------------------------------
__global__ __launch_bounds__(256) void mode_exc(
    const int* __restrict__ DE, int* __restrict__ modeInfo,
    int* __restrict__ exc_idx, float* __restrict__ exc_delta) {
  __shared__ unsigned hist[1024];
  __shared__ int s_mode;
  __shared__ int s_cnt;
  const int tid = threadIdx.x;
  for (int i = tid; i < 1024; i += 256) hist[i] = 0u;
  __syncthreads();
  for (int e = tid; e < EE; e += 256) atomicAdd(&hist[DE[e]], 1u);
  __syncthreads();
  if (tid == 0) {
    int best = 1; unsigned bc = 0;
    for (int i = 0; i < 1024; ++i)
      if (hist[i] > bc) { bc = hist[i]; best = i; }
    s_mode = best; s_cnt = 0;
  }
  __syncthreads();
  const int mode = s_mode;
  const float invMode = 1.0f / (float)mode;
  for (int e = tid; e < EE; e += 256) {
    const int de = DE[e];
    if (de != mode) {
      const int idx = atomicAdd(&s_cnt, 1);
      exc_idx[idx] = e;
      exc_delta[idx] = 1.0f / (float)de - invMode;
    }
  }
  __syncthreads();
  if (tid == 0) {
    modeInfo[0] = s_mode;
    modeInfo[1] = s_cnt;
    modeInfo[2] = __float_as_int(invMode);
  }
}

// ---------------------------------------------------------------------------
// Kernel 5: G = DV2 (H H^T ./ DE) DV2 via i8 MFMA GEMM (exact i32 counts)
// 128x128 tile, BK=128 bytes, 4 waves, 16x16x64 i8 MFMA, m97 structure:
// global_load_lds width-16 staging (linear dest, inverse-swizzled source) +
// XOR-swizzled ds_read_b128 (2-way conflicts only).
// ---------------------------------------------------------------------------
__global__ __launch_bounds__(256) void g_mfma(
    const unsigned char* __restrict__ H8, const float* __restrict__ DV2,
    const int* __restrict__ modeInfo, const int* __restrict__ exc_idx,
    const float* __restrict__ exc_delta,
    const unsigned long long* __restrict__ Hbits, float* __restrict__ G) {
  __shared__ unsigned char As[128 * 128];
  __shared__ unsigned char Bs[128 * 128];
  __shared__ float sDVr[128], sDVc[128];
  const int tid = threadIdx.x;
  const int lane = tid & 63;
  const int wave = tid >> 6;
  const int bi = blockIdx.y, bj = blockIdx.x;
  if (tid < 128) sDVr[tid] = DV2[bi * 128 + tid];
  else sDVc[tid - 128] = DV2[bj * 128 + (tid - 128)];

  const unsigned char* Ag = H8 + (size_t)bi * 128 * EE;
  const unsigned char* Bg = H8 + (size_t)bj * 128 * EE;

  int32x4 acc[4][4];
  const int32x4 zero = {0, 0, 0, 0};
#pragma unroll
  for (int m = 0; m < 4; ++m)
#pragma unroll
    for (int n = 0; n < 4; ++n) acc[m][n] = zero;

  const int wr = wave >> 1, wc = wave & 1;

  for (int s = 0; s < 8; ++s) {
    const int kbase = s * 128;
    // stage A,B tiles: per wave 4 chunks of 64 lanes x 16B each, linear LDS dest
#pragma unroll
    for (int q = 0; q < 4; ++q) {
      const int chunk = wave * 256 + q * 64 + lane;
      const int r = chunk >> 3;              // row in tile [0,128)
      const int cq = (chunk & 7) * 16;       // dest k-offset [0,128)
      const int csrc = cq ^ ((r & 7) << 4);  // inverse-swizzled source column
      __builtin_amdgcn_global_load_lds(
          (const __attribute__((address_space(1))) void*)(Ag + (size_t)r * EE + kbase + csrc),
          (__attribute__((address_space(3))) void*)(As + (wave * 256 + q * 64) * 16),
          16, 0, 0);
      __builtin_amdgcn_global_load_lds(
          (const __attribute__((address_space(1))) void*)(Bg + (size_t)r * EE + kbase + csrc),
          (__attribute__((address_space(3))) void*)(Bs + (wave * 256 + q * 64) * 16),
          16, 0, 0);
    }
    __syncthreads();
#pragma unroll
    for (int ks = 0; ks < 2; ++ks) {
      int32x4 af[4], bf[4];
#pragma unroll
      for (int m = 0; m < 4; ++m) {
        const int r = wr * 64 + m * 16 + (lane & 15);
        const int c = ks * 64 + (lane >> 4) * 16;
        af[m] = *(const int32x4*)&As[r * 128 + (c ^ ((r & 7) << 4))];
      }
#pragma unroll
      for (int n = 0; n < 4; ++n) {
        const int r = wc * 64 + n * 16 + (lane & 15);
        const int c = ks * 64 + (lane >> 4) * 16;
        bf[n] = *(const int32x4*)&Bs[r * 128 + (c ^ ((r & 7) << 4))];
      }
#pragma unroll
      for (int m = 0; m < 4; ++m)
#pragma unroll
        for (int n = 0; n < 4; ++n)
          acc[m][n] = __builtin_amdgcn_mfma_i32_16x16x64_i8(af[m], bf[n], acc[m][n], 0, 0, 0);
    }
    __syncthreads();
  }

  // epilogue: scale by invMode, rare exception corrections, DV2 outer scale
  const float invMode = __int_as_float(modeInfo[2]);
  const int NX = modeInfo[1];
  const int l4 = lane >> 4;
  const int lc = lane & 15;
#pragma unroll
  for (int m = 0; m < 4; ++m) {
#pragma unroll
    for (int n = 0; n < 4; ++n) {
#pragma unroll
      for (int reg = 0; reg < 4; ++reg) {
        const int Rl = wr * 64 + m * 16 + l4 * 4 + reg;
        const int Cl = wc * 64 + n * 16 + lc;
        const int Rg = bi * 128 + Rl;
        const int Cg = bj * 128 + Cl;
        float v = (float)acc[m][n][reg] * invMode;
        for (int xx = 0; xx < NX; ++xx) {
          const int e = exc_idx[xx];
          const int w = e >> 6, b = e & 63;
          const unsigned long long rb = Hbits[(size_t)Rg * 16 + w] >> b;
          const unsigned long long cb = Hbits[(size_t)Cg * 16 + w] >> b;
          v += exc_delta[xx] * (float)(rb & cb & 1ull);
        }
        G[(size_t)Rg * NN + Cg] = v * sDVr[Rl] * sDVc[Cl];
      }
    }
  }
}

// ---------------------------------------------------------------------------
extern "C" void kernel_launch(void* const* d_in, const int* in_sizes, int n_in,
                              void* d_out, int out_size, void* d_ws, size_t ws_size,
                              hipStream_t stream) {
  const float* x = (const float*)d_in[0];        // [64,128,256]
  const int* y = (const int*)d_in[1];            // [64]
  const float* hyper = (const float*)d_in[2];    // [100,16,256]
  float* out = (float*)d_out;                    // G [8192*8192] then hyper_x [8192*256]

  // simi (32 MB) lives inside d_out's G region (G written only afterwards).
  float* simi = out;
  // H8 (8 MB = 8192*1024 i8) lives in the hyper_x slot, overwritten at the end.
  unsigned char* H8 = (unsigned char*)(out + (size_t)NN * NN);

  uint8_t* w8 = (uint8_t*)d_ws;
  float* thr = (float*)(w8 + 0);                            // 4 KB
  int* DE = (int*)(w8 + 4096);                              // 4 KB
  float* DV2 = (float*)(w8 + 8192);                         // 32 KB
  int* modeInfo = (int*)(w8 + 40960);                       // 16 B
  int* exc_idx = (int*)(w8 + 41984);                        // 4 KB
  float* exc_delta = (float*)(w8 + 46080);                  // 4 KB
  unsigned long long* Hbits = (unsigned long long*)(w8 + 65536);  // 1 MB

  simi_gemm<<<dim3(NN / 64, EE / 64), 256, 0, stream>>>(x, y, hyper, simi);
  select_thr<<<dim3(EE), 256, 0, stream>>>(simi, thr, DE);
  build_h<<<dim3(NN / 256), 256, 0, stream>>>(simi, thr, Hbits, DV2);
  h8_expand<<<dim3(NN * 64 / 256), 256, 0, stream>>>(Hbits, H8);
  mode_exc<<<dim3(1), 256, 0, stream>>>(DE, modeInfo, exc_idx, exc_delta);
  g_mfma<<<dim3(NN / 128, NN / 128), 256, 0, stream>>>(H8, DV2, modeInfo,
                                                       exc_idx, exc_delta, Hbits, out);
  hipMemcpyAsync(out + (size_t)NN * NN, x, (size_t)NN * DD * sizeof(float),
                 hipMemcpyDeviceToDevice, stream);
}